// Round 9
// baseline (1029.001 us; speedup 1.0000x reference)
//
#include <hip/hip_runtime.h>
#include <math.h>

#define N_NODES 100000
#define N_EDGES 3200000
#define H 10
#define S 12          // padded per-node stride (floats): 48B, float4-aligned
#define IN_DIM 16
#define NB 128        // nodes per bucket
#define NBKT 782      // ceil(N_NODES / NB)
#define BCAP 4608     // edge capacity per bucket (mean 4096, +8 sigma)
#define FTILE 8192    // edges per fill block (32 per thread @256)
#define NFB 391       // ceil(N_EDGES / FTILE)
#define GT 512        // gather block threads (8 waves)

typedef int nint4 __attribute__((ext_vector_type(4)));

// ============ bptr init: bucket write cursors at fixed-stride starts ============
__global__ __launch_bounds__(256) void k_binit(int* __restrict__ bptr)
{
    int i = blockIdx.x * 256 + threadIdx.x;
    if (i < NBKT) bptr[i] = i * BCAP;
}

// ---- bf16 pack (round-to-nearest-even) ----
__device__ __forceinline__ unsigned pack2bf(float a, float b)
{
    unsigned ua = __float_as_uint(a), ub = __float_as_uint(b);
    unsigned ra = (ua + 0x7FFFu + ((ua >> 16) & 1u)) >> 16;
    unsigned rb = (ub + 0x7FFFu + ((ub >> 16) & 1u)) >> 16;
    return ra | (rb << 16);
}

// ============ fill: tile-sorted scatter into bucket regions ============
// (EXACT round-6 passing version)
// entry = 16B {bf16(a0,a1), bf16(a2,a3), row, col_local}
__global__ __launch_bounds__(256) void k_fill(const int* __restrict__ ei,
    const float* __restrict__ attr, int* __restrict__ bptr,
    nint4* __restrict__ entries)
{
    __shared__ int lcnt[NBKT];
    __shared__ int lbase[NBKT];
    int tid = threadIdx.x;
    int base = blockIdx.x * FTILE;
    for (int k = tid; k < NBKT; k += 256) lcnt[k] = 0;
    __syncthreads();
    int c[32];
    #pragma unroll
    for (int k = 0; k < 32; ++k) {
        int e = base + k * 256 + tid;
        c[k] = (e < N_EDGES) ? ei[N_EDGES + e] : -1;
        if (c[k] >= 0) atomicAdd(&lcnt[c[k] >> 7], 1);
    }
    __syncthreads();
    for (int k = tid; k < NBKT; k += 256) {
        int n = lcnt[k];
        lbase[k] = n ? atomicAdd(&bptr[k], n) : 0;   // absolute entry index
        lcnt[k] = 0;
    }
    __syncthreads();
    #pragma unroll
    for (int k = 0; k < 32; ++k) {
        if (c[k] < 0) continue;
        int e = base + k * 256 + tid;
        int b = c[k] >> 7;
        int slot = atomicAdd(&lcnt[b], 1);
        int dest = lbase[b] + slot;
        if (dest < (b + 1) * BCAP) {                  // overflow guard (never fires)
            float4 a = ((const float4*)attr)[e];
            nint4 v;
            v.x = (int)pack2bf(a.x, a.y);
            v.y = (int)pack2bf(a.z, a.w);
            v.z = ei[e];
            v.w = c[k] & (NB - 1);
            __builtin_nontemporal_store(v, &entries[dest]);
        }
    }
}

// ============ shared helper: ew from packed attr ============
__device__ __forceinline__ void ew_from_packed(int px, int py,
    const float* sW1, const float* sW2, float ew[H])
{
    float ax = __uint_as_float(((unsigned)px) << 16);
    float ay = __uint_as_float(((unsigned)px) & 0xffff0000u);
    float az = __uint_as_float(((unsigned)py) << 16);
    float aw = __uint_as_float(((unsigned)py) & 0xffff0000u);
    float tt[H];
    #pragma unroll
    for (int j = 0; j < H; ++j)
        tt[j] = fmaxf(fmaf(ax, sW1[j], fmaf(ay, sW1[H+j],
                      fmaf(az, sW1[2*H+j], aw*sW1[3*H+j]))), 0.f);
    #pragma unroll
    for (int ch = 0; ch < H; ++ch) {
        float v = 0.f;
        #pragma unroll
        for (int j = 0; j < H; ++j) v = fmaf(tt[j], sW2[j*H + ch], v);
        ew[ch] = fmaxf(v, 0.f);
    }
}

// ============ deg pass (fused, round-6 structure, GT threads):
//  LDS-accumulate deg; epilogue x_ = x@iW+ib ; dinv ; u0 ============
__global__ __launch_bounds__(GT) void k_deg(const nint4* __restrict__ entries,
    const int* __restrict__ bptr,
    const float* __restrict__ W1, const float* __restrict__ W2,
    const float* __restrict__ x, const float* __restrict__ iW,
    const float* __restrict__ ib, const float* __restrict__ gw0,
    float* __restrict__ x_, float* __restrict__ dinv, float* __restrict__ u)
{
    __shared__ float sW1[4*H], sW2[H*H], siW[IN_DIM*H], sib[H], sgw[H];
    __shared__ float acc[NB*H];
    int tid = threadIdx.x;
    for (int k = tid; k < 4*H; k += GT) sW1[k] = W1[k];
    for (int k = tid; k < H*H; k += GT) sW2[k] = W2[k];
    for (int k = tid; k < IN_DIM*H; k += GT) siW[k] = iW[k];
    if (tid < H) sib[tid] = ib[tid];
    if (tid >= 32 && tid < 32+H) sgw[tid-32] = gw0[tid-32];
    for (int k = tid; k < NB*H; k += GT) acc[k] = 0.f;
    __syncthreads();
    int b = blockIdx.x;
    int st = b * BCAP;
    int en = min(bptr[b], st + BCAP);
    for (int e = st + tid; e < en; e += GT) {
        nint4 ent = entries[e];
        float ew[H];
        ew_from_packed(ent.x, ent.y, sW1, sW2, ew);
        float* ac = &acc[ent.w * H];
        #pragma unroll
        for (int ch = 0; ch < H; ++ch) atomicAdd(&ac[ch], ew[ch]);
    }
    __syncthreads();
    int node = b * NB + tid;
    if (tid < NB && node < N_NODES) {
        const float4* xv4 = (const float4*)(x + (size_t)node * IN_DIM);
        float xi[IN_DIM];
        float4 a0 = xv4[0], a1 = xv4[1], a2 = xv4[2], a3 = xv4[3];
        xi[0]=a0.x; xi[1]=a0.y; xi[2]=a0.z; xi[3]=a0.w;
        xi[4]=a1.x; xi[5]=a1.y; xi[6]=a1.z; xi[7]=a1.w;
        xi[8]=a2.x; xi[9]=a2.y; xi[10]=a2.z; xi[11]=a2.w;
        xi[12]=a3.x; xi[13]=a3.y; xi[14]=a3.z; xi[15]=a3.w;
        float xb[H], dv[H], uu[H];
        #pragma unroll
        for (int j = 0; j < H; ++j) {
            float a = sib[j];
            #pragma unroll
            for (int k = 0; k < IN_DIM; ++k) a = fmaf(xi[k], siW[k*H + j], a);
            xb[j] = a;
        }
        const float* ac = &acc[tid * H];
        #pragma unroll
        for (int ch = 0; ch < H; ++ch) {
            float di = rsqrtf(1.0f + ac[ch]);
            dv[ch] = di;
            uu[ch] = di * fmaxf(xb[ch], 0.f) * sgw[ch];
        }
        float* xd = x_   + (size_t)node * S;
        float* dd = dinv + (size_t)node * S;
        float* ud = u    + (size_t)node * S;
        *(float4*)(xd+0) = make_float4(xb[0],xb[1],xb[2],xb[3]);
        *(float4*)(xd+4) = make_float4(xb[4],xb[5],xb[6],xb[7]);
        *(float4*)(xd+8) = make_float4(xb[8],xb[9],0.f,0.f);
        *(float4*)(dd+0) = make_float4(dv[0],dv[1],dv[2],dv[3]);
        *(float4*)(dd+4) = make_float4(dv[4],dv[5],dv[6],dv[7]);
        *(float4*)(dd+8) = make_float4(dv[8],dv[9],0.f,0.f);
        *(float4*)(ud+0) = make_float4(uu[0],uu[1],uu[2],uu[3]);
        *(float4*)(ud+4) = make_float4(uu[4],uu[5],uu[6],uu[7]);
        *(float4*)(ud+8) = make_float4(uu[8],uu[9],0.f,0.f);
    }
}

// ============ fused layer (round-6 structure, GT threads) ============
template<int LAST>
__global__ __launch_bounds__(GT) void k_layer(const nint4* __restrict__ entries,
    const int* __restrict__ bptr,
    const float* __restrict__ W1, const float* __restrict__ W2,
    const float* __restrict__ x_, const float* __restrict__ dinv,
    const float* __restrict__ uin, const float* __restrict__ lin,
    const float* __restrict__ gw_next, const float* __restrict__ gb,
    const float* __restrict__ oW, float* __restrict__ uout, float* __restrict__ out)
{
    __shared__ float sW1[4*H], sW2[H*H], slin[2*H*H], sgw[H], sgb[H], soW[4*H];
    __shared__ float acc[NB*H];
    int tid = threadIdx.x;
    for (int k = tid; k < 4*H; k += GT) sW1[k] = W1[k];
    for (int k = tid; k < H*H; k += GT) sW2[k] = W2[k];
    for (int k = tid; k < 2*H*H; k += GT) slin[k] = lin[k];
    if (tid < H) sgb[tid] = gb[tid];
    if (LAST) { if (tid >= 32 && tid < 32+4*H) soW[tid-32] = oW[tid-32]; }
    else      { if (tid >= 32 && tid < 32+H)   sgw[tid-32] = gw_next[tid-32]; }
    for (int k = tid; k < NB*H; k += GT) acc[k] = 0.f;
    __syncthreads();
    int b = blockIdx.x;
    int st = b * BCAP;
    int en = min(bptr[b], st + BCAP);
    for (int e = st + tid; e < en; e += GT) {
        nint4 ent = entries[e];
        const float4* up = (const float4*)(uin + (size_t)ent.z * S);
        float4 u0 = up[0], u1 = up[1], u2 = up[2];
        float ew[H];
        ew_from_packed(ent.x, ent.y, sW1, sW2, ew);
        float ur[H];
        ur[0]=u0.x; ur[1]=u0.y; ur[2]=u0.z; ur[3]=u0.w;
        ur[4]=u1.x; ur[5]=u1.y; ur[6]=u1.z; ur[7]=u1.w;
        ur[8]=u2.x; ur[9]=u2.y;
        float* ac = &acc[ent.w * H];
        #pragma unroll
        for (int ch = 0; ch < H; ++ch) atomicAdd(&ac[ch], ew[ch] * ur[ch]);
    }
    __syncthreads();
    int node = b * NB + tid;
    if (tid < NB && node < N_NODES) {
        const float* xi = x_   + (size_t)node * S;
        const float* di = dinv + (size_t)node * S;
        const float* ui = uin  + (size_t)node * S;
        const float* ac = &acc[tid * H];
        float xv[H], agg[H];
        #pragma unroll
        for (int ch = 0; ch < H; ++ch) {
            xv[ch] = xi[ch];
            agg[ch] = di[ch] * (ac[ch] + ui[ch]) + sgb[ch];  // self-loop folded in
        }
        float h[H];
        #pragma unroll
        for (int j = 0; j < H; ++j) {
            float a = xv[j];                                  // residual
            #pragma unroll
            for (int k = 0; k < H; ++k) a = fmaf(xv[k], slin[k*H + j], a);
            #pragma unroll
            for (int k = 0; k < H; ++k) a = fmaf(agg[k], slin[(H+k)*H + j], a);
            h[j] = a;
        }
        if (!LAST) {
            float un[H];
            #pragma unroll
            for (int ch = 0; ch < H; ++ch)
                un[ch] = di[ch] * fmaxf(h[ch], 0.f) * sgw[ch];
            float* ud = uout + (size_t)node * S;
            *(float4*)(ud+0) = make_float4(un[0],un[1],un[2],un[3]);
            *(float4*)(ud+4) = make_float4(un[4],un[5],un[6],un[7]);
            *(float4*)(ud+8) = make_float4(un[8],un[9],0.f,0.f);
        } else {
            float z0 = 0.f, z1 = 0.f;
            #pragma unroll
            for (int k = 0; k < H; ++k) { z0 = fmaf(xv[k], soW[2*k],   z0);
                                          z1 = fmaf(xv[k], soW[2*k+1], z1); }
            #pragma unroll
            for (int k = 0; k < H; ++k) { float hr = fmaxf(h[k], 0.f);
                                          z0 = fmaf(hr, soW[2*(H+k)],   z0);
                                          z1 = fmaf(hr, soW[2*(H+k)+1], z1); }
            out[node] = 1.0f / (1.0f + expf(z0 - z1));
        }
    }
}

extern "C" void kernel_launch(void* const* d_in, const int* in_sizes, int n_in,
                              void* d_out, int out_size, void* d_ws, size_t ws_size,
                              hipStream_t stream)
{
    const float* x     = (const float*)d_in[0];
    const int*   ei    = (const int*)  d_in[1];
    const float* attr  = (const float*)d_in[2];
    const float* ew_W1 = (const float*)d_in[3];
    const float* ew_W2 = (const float*)d_in[4];
    const float* iW    = (const float*)d_in[5];
    const float* ib    = (const float*)d_in[6];
    const float* gcn_w = (const float*)d_in[7];
    const float* gcn_b = (const float*)d_in[8];
    const float* lin_W = (const float*)d_in[9];
    const float* oW    = (const float*)d_in[10];
    float* out = (float*)d_out;
    char* ws = (char*)d_ws;

    size_t o = 0;
    nint4* entries = (nint4*)(ws + o); o += (size_t)NBKT * BCAP * 16;      // 57.7 MB
    float* x_   = (float*)(ws + o); o += (size_t)N_NODES * S * 4;          // 4.8 MB each
    float* dinv = (float*)(ws + o); o += (size_t)N_NODES * S * 4;
    float* u_a  = (float*)(ws + o); o += (size_t)N_NODES * S * 4;
    float* u_b  = (float*)(ws + o); o += (size_t)N_NODES * S * 4;
    int* bptr   = (int*)(ws + o); o += (size_t)NBKT * 4;

    k_binit<<<(NBKT + 255) / 256, 256, 0, stream>>>(bptr);
    k_fill <<<NFB, 256, 0, stream>>>(ei, attr, bptr, entries);

    k_deg  <<<NBKT, GT, 0, stream>>>(entries, bptr, ew_W1, ew_W2,
                                     x, iW, ib, gcn_w, x_, dinv, u_a);
    // layer 0: u_a -> u_b
    k_layer<0><<<NBKT, GT, 0, stream>>>(entries, bptr, ew_W1, ew_W2,
        x_, dinv, u_a, lin_W + 0*2*H*H, gcn_w + 1*H, gcn_b + 0*H, oW, u_b, out);
    // layer 1: u_b -> u_a
    k_layer<0><<<NBKT, GT, 0, stream>>>(entries, bptr, ew_W1, ew_W2,
        x_, dinv, u_b, lin_W + 1*2*H*H, gcn_w + 2*H, gcn_b + 1*H, oW, u_a, out);
    // layer 2: u_a -> out
    k_layer<1><<<NBKT, GT, 0, stream>>>(entries, bptr, ew_W1, ew_W2,
        x_, dinv, u_a, lin_W + 2*2*H*H, nullptr, gcn_b + 2*H, oW, nullptr, out);
}

// Round 10
// 1028.262 us; speedup vs baseline: 1.0007x; 1.0007x over previous
//
#include <hip/hip_runtime.h>
#include <math.h>

#define N_NODES 100000
#define N_EDGES 3200000
#define H 10
#define S 12          // padded per-node stride (floats): 48B, float4-aligned
#define IN_DIM 16
#define NB 128        // nodes per bucket
#define NBKT 782      // ceil(N_NODES / NB)
#define BCAP 4608     // edge capacity per bucket (mean 4096, +8 sigma)
#define FTILE 8192    // edges per fill block (32 per thread @256)
#define NFB 391       // ceil(N_EDGES / FTILE)
#define GT 512        // gather block threads (8 waves)

typedef int nint4 __attribute__((ext_vector_type(4)));

// ============ bptr init: bucket write cursors at fixed-stride starts ============
__global__ __launch_bounds__(256) void k_binit(int* __restrict__ bptr)
{
    int i = blockIdx.x * 256 + threadIdx.x;
    if (i < NBKT) bptr[i] = i * BCAP;
}

// ---- bf16 pack (round-to-nearest-even) ----
__device__ __forceinline__ unsigned pack2bf(float a, float b)
{
    unsigned ua = __float_as_uint(a), ub = __float_as_uint(b);
    unsigned ra = (ua + 0x7FFFu + ((ua >> 16) & 1u)) >> 16;
    unsigned rb = (ub + 0x7FFFu + ((ub >> 16) & 1u)) >> 16;
    return ra | (rb << 16);
}

// ============ fill: tile-sorted scatter into bucket regions ============
// entry = 16B {bf16(a0,a1), bf16(a2,a3), row, col_local}
__global__ __launch_bounds__(256) void k_fill(const int* __restrict__ ei,
    const float* __restrict__ attr, int* __restrict__ bptr,
    nint4* __restrict__ entries)
{
    __shared__ int lcnt[NBKT];
    __shared__ int lbase[NBKT];
    int tid = threadIdx.x;
    int base = blockIdx.x * FTILE;
    for (int k = tid; k < NBKT; k += 256) lcnt[k] = 0;
    __syncthreads();
    int c[32];
    #pragma unroll
    for (int k = 0; k < 32; ++k) {
        int e = base + k * 256 + tid;
        c[k] = (e < N_EDGES) ? ei[N_EDGES + e] : -1;
        if (c[k] >= 0) atomicAdd(&lcnt[c[k] >> 7], 1);
    }
    __syncthreads();
    for (int k = tid; k < NBKT; k += 256) {
        int n = lcnt[k];
        lbase[k] = n ? atomicAdd(&bptr[k], n) : 0;   // absolute entry index
        lcnt[k] = 0;
    }
    __syncthreads();
    #pragma unroll
    for (int k = 0; k < 32; ++k) {
        if (c[k] < 0) continue;
        int e = base + k * 256 + tid;
        int b = c[k] >> 7;
        int slot = atomicAdd(&lcnt[b], 1);
        int dest = lbase[b] + slot;
        if (dest < (b + 1) * BCAP) {                  // overflow guard (never fires)
            float4 a = ((const float4*)attr)[e];
            nint4 v;
            v.x = (int)pack2bf(a.x, a.y);
            v.y = (int)pack2bf(a.z, a.w);
            v.z = ei[e];
            v.w = c[k] & (NB - 1);
            __builtin_nontemporal_store(v, &entries[dest]);
        }
    }
}

// ============ shared helper: ew from packed attr ============
__device__ __forceinline__ void ew_from_packed(int px, int py,
    const float* sW1, const float* sW2, float ew[H])
{
    float ax = __uint_as_float(((unsigned)px) << 16);
    float ay = __uint_as_float(((unsigned)px) & 0xffff0000u);
    float az = __uint_as_float(((unsigned)py) << 16);
    float aw = __uint_as_float(((unsigned)py) & 0xffff0000u);
    float tt[H];
    #pragma unroll
    for (int j = 0; j < H; ++j)
        tt[j] = fmaxf(fmaf(ax, sW1[j], fmaf(ay, sW1[H+j],
                      fmaf(az, sW1[2*H+j], aw*sW1[3*H+j]))), 0.f);
    #pragma unroll
    for (int ch = 0; ch < H; ++ch) {
        float v = 0.f;
        #pragma unroll
        for (int j = 0; j < H; ++j) v = fmaf(tt[j], sW2[j*H + ch], v);
        ew[ch] = fmaxf(v, 0.f);
    }
}

// ============ deg pass (fused): LDS-accumulate deg (native ds_add_f32);
//  epilogue x_ = x@iW+ib ; dinv ; u0 ============
__global__ __launch_bounds__(GT) void k_deg(const nint4* __restrict__ entries,
    const int* __restrict__ bptr,
    const float* __restrict__ W1, const float* __restrict__ W2,
    const float* __restrict__ x, const float* __restrict__ iW,
    const float* __restrict__ ib, const float* __restrict__ gw0,
    float* __restrict__ x_, float* __restrict__ dinv, float* __restrict__ u)
{
    __shared__ float sW1[4*H], sW2[H*H], siW[IN_DIM*H], sib[H], sgw[H];
    __shared__ float acc[NB*H];
    int tid = threadIdx.x;
    for (int k = tid; k < 4*H; k += GT) sW1[k] = W1[k];
    for (int k = tid; k < H*H; k += GT) sW2[k] = W2[k];
    for (int k = tid; k < IN_DIM*H; k += GT) siW[k] = iW[k];
    if (tid < H) sib[tid] = ib[tid];
    if (tid >= 32 && tid < 32+H) sgw[tid-32] = gw0[tid-32];
    for (int k = tid; k < NB*H; k += GT) acc[k] = 0.f;
    __syncthreads();
    int b = blockIdx.x;
    int st = b * BCAP;
    int en = min(bptr[b], st + BCAP);
    for (int e = st + tid; e < en; e += GT) {
        nint4 ent = entries[e];
        float ew[H];
        ew_from_packed(ent.x, ent.y, sW1, sW2, ew);
        float* ac = &acc[ent.w * H];
        #pragma unroll
        for (int ch = 0; ch < H; ++ch) unsafeAtomicAdd(&ac[ch], ew[ch]);
    }
    __syncthreads();
    int node = b * NB + tid;
    if (tid < NB && node < N_NODES) {
        const float4* xv4 = (const float4*)(x + (size_t)node * IN_DIM);
        float xi[IN_DIM];
        float4 a0 = xv4[0], a1 = xv4[1], a2 = xv4[2], a3 = xv4[3];
        xi[0]=a0.x; xi[1]=a0.y; xi[2]=a0.z; xi[3]=a0.w;
        xi[4]=a1.x; xi[5]=a1.y; xi[6]=a1.z; xi[7]=a1.w;
        xi[8]=a2.x; xi[9]=a2.y; xi[10]=a2.z; xi[11]=a2.w;
        xi[12]=a3.x; xi[13]=a3.y; xi[14]=a3.z; xi[15]=a3.w;
        float xb[H], dv[H], uu[H];
        #pragma unroll
        for (int j = 0; j < H; ++j) {
            float a = sib[j];
            #pragma unroll
            for (int k = 0; k < IN_DIM; ++k) a = fmaf(xi[k], siW[k*H + j], a);
            xb[j] = a;
        }
        const float* ac = &acc[tid * H];
        #pragma unroll
        for (int ch = 0; ch < H; ++ch) {
            float di = rsqrtf(1.0f + ac[ch]);
            dv[ch] = di;
            uu[ch] = di * fmaxf(xb[ch], 0.f) * sgw[ch];
        }
        float* xd = x_   + (size_t)node * S;
        float* dd = dinv + (size_t)node * S;
        float* ud = u    + (size_t)node * S;
        *(float4*)(xd+0) = make_float4(xb[0],xb[1],xb[2],xb[3]);
        *(float4*)(xd+4) = make_float4(xb[4],xb[5],xb[6],xb[7]);
        *(float4*)(xd+8) = make_float4(xb[8],xb[9],0.f,0.f);
        *(float4*)(dd+0) = make_float4(dv[0],dv[1],dv[2],dv[3]);
        *(float4*)(dd+4) = make_float4(dv[4],dv[5],dv[6],dv[7]);
        *(float4*)(dd+8) = make_float4(dv[8],dv[9],0.f,0.f);
        *(float4*)(ud+0) = make_float4(uu[0],uu[1],uu[2],uu[3]);
        *(float4*)(ud+4) = make_float4(uu[4],uu[5],uu[6],uu[7]);
        *(float4*)(ud+8) = make_float4(uu[8],uu[9],0.f,0.f);
    }
}

// ============ fused layer (native ds_add_f32 accumulate) ============
template<int LAST>
__global__ __launch_bounds__(GT) void k_layer(const nint4* __restrict__ entries,
    const int* __restrict__ bptr,
    const float* __restrict__ W1, const float* __restrict__ W2,
    const float* __restrict__ x_, const float* __restrict__ dinv,
    const float* __restrict__ uin, const float* __restrict__ lin,
    const float* __restrict__ gw_next, const float* __restrict__ gb,
    const float* __restrict__ oW, float* __restrict__ uout, float* __restrict__ out)
{
    __shared__ float sW1[4*H], sW2[H*H], slin[2*H*H], sgw[H], sgb[H], soW[4*H];
    __shared__ float acc[NB*H];
    int tid = threadIdx.x;
    for (int k = tid; k < 4*H; k += GT) sW1[k] = W1[k];
    for (int k = tid; k < H*H; k += GT) sW2[k] = W2[k];
    for (int k = tid; k < 2*H*H; k += GT) slin[k] = lin[k];
    if (tid < H) sgb[tid] = gb[tid];
    if (LAST) { if (tid >= 32 && tid < 32+4*H) soW[tid-32] = oW[tid-32]; }
    else      { if (tid >= 32 && tid < 32+H)   sgw[tid-32] = gw_next[tid-32]; }
    for (int k = tid; k < NB*H; k += GT) acc[k] = 0.f;
    __syncthreads();
    int b = blockIdx.x;
    int st = b * BCAP;
    int en = min(bptr[b], st + BCAP);
    for (int e = st + tid; e < en; e += GT) {
        nint4 ent = entries[e];
        const float4* up = (const float4*)(uin + (size_t)ent.z * S);
        float4 u0 = up[0], u1 = up[1], u2 = up[2];
        float ew[H];
        ew_from_packed(ent.x, ent.y, sW1, sW2, ew);
        float ur[H];
        ur[0]=u0.x; ur[1]=u0.y; ur[2]=u0.z; ur[3]=u0.w;
        ur[4]=u1.x; ur[5]=u1.y; ur[6]=u1.z; ur[7]=u1.w;
        ur[8]=u2.x; ur[9]=u2.y;
        float* ac = &acc[ent.w * H];
        #pragma unroll
        for (int ch = 0; ch < H; ++ch) unsafeAtomicAdd(&ac[ch], ew[ch] * ur[ch]);
    }
    __syncthreads();
    int node = b * NB + tid;
    if (tid < NB && node < N_NODES) {
        const float* xi = x_   + (size_t)node * S;
        const float* di = dinv + (size_t)node * S;
        const float* ui = uin  + (size_t)node * S;
        const float* ac = &acc[tid * H];
        float xv[H], agg[H];
        #pragma unroll
        for (int ch = 0; ch < H; ++ch) {
            xv[ch] = xi[ch];
            agg[ch] = di[ch] * (ac[ch] + ui[ch]) + sgb[ch];  // self-loop folded in
        }
        float h[H];
        #pragma unroll
        for (int j = 0; j < H; ++j) {
            float a = xv[j];                                  // residual
            #pragma unroll
            for (int k = 0; k < H; ++k) a = fmaf(xv[k], slin[k*H + j], a);
            #pragma unroll
            for (int k = 0; k < H; ++k) a = fmaf(agg[k], slin[(H+k)*H + j], a);
            h[j] = a;
        }
        if (!LAST) {
            float un[H];
            #pragma unroll
            for (int ch = 0; ch < H; ++ch)
                un[ch] = di[ch] * fmaxf(h[ch], 0.f) * sgw[ch];
            float* ud = uout + (size_t)node * S;
            *(float4*)(ud+0) = make_float4(un[0],un[1],un[2],un[3]);
            *(float4*)(ud+4) = make_float4(un[4],un[5],un[6],un[7]);
            *(float4*)(ud+8) = make_float4(un[8],un[9],0.f,0.f);
        } else {
            float z0 = 0.f, z1 = 0.f;
            #pragma unroll
            for (int k = 0; k < H; ++k) { z0 = fmaf(xv[k], soW[2*k],   z0);
                                          z1 = fmaf(xv[k], soW[2*k+1], z1); }
            #pragma unroll
            for (int k = 0; k < H; ++k) { float hr = fmaxf(h[k], 0.f);
                                          z0 = fmaf(hr, soW[2*(H+k)],   z0);
                                          z1 = fmaf(hr, soW[2*(H+k)+1], z1); }
            out[node] = 1.0f / (1.0f + expf(z0 - z1));
        }
    }
}

extern "C" void kernel_launch(void* const* d_in, const int* in_sizes, int n_in,
                              void* d_out, int out_size, void* d_ws, size_t ws_size,
                              hipStream_t stream)
{
    const float* x     = (const float*)d_in[0];
    const int*   ei    = (const int*)  d_in[1];
    const float* attr  = (const float*)d_in[2];
    const float* ew_W1 = (const float*)d_in[3];
    const float* ew_W2 = (const float*)d_in[4];
    const float* iW    = (const float*)d_in[5];
    const float* ib    = (const float*)d_in[6];
    const float* gcn_w = (const float*)d_in[7];
    const float* gcn_b = (const float*)d_in[8];
    const float* lin_W = (const float*)d_in[9];
    const float* oW    = (const float*)d_in[10];
    float* out = (float*)d_out;
    char* ws = (char*)d_ws;

    size_t o = 0;
    nint4* entries = (nint4*)(ws + o); o += (size_t)NBKT * BCAP * 16;      // 57.7 MB
    float* x_   = (float*)(ws + o); o += (size_t)N_NODES * S * 4;          // 4.8 MB each
    float* dinv = (float*)(ws + o); o += (size_t)N_NODES * S * 4;
    float* u_a  = (float*)(ws + o); o += (size_t)N_NODES * S * 4;
    float* u_b  = (float*)(ws + o); o += (size_t)N_NODES * S * 4;
    int* bptr   = (int*)(ws + o); o += (size_t)NBKT * 4;

    k_binit<<<(NBKT + 255) / 256, 256, 0, stream>>>(bptr);
    k_fill <<<NFB, 256, 0, stream>>>(ei, attr, bptr, entries);

    k_deg  <<<NBKT, GT, 0, stream>>>(entries, bptr, ew_W1, ew_W2,
                                     x, iW, ib, gcn_w, x_, dinv, u_a);
    // layer 0: u_a -> u_b
    k_layer<0><<<NBKT, GT, 0, stream>>>(entries, bptr, ew_W1, ew_W2,
        x_, dinv, u_a, lin_W + 0*2*H*H, gcn_w + 1*H, gcn_b + 0*H, oW, u_b, out);
    // layer 1: u_b -> u_a
    k_layer<0><<<NBKT, GT, 0, stream>>>(entries, bptr, ew_W1, ew_W2,
        x_, dinv, u_b, lin_W + 1*2*H*H, gcn_w + 2*H, gcn_b + 1*H, oW, u_a, out);
    // layer 2: u_a -> out
    k_layer<1><<<NBKT, GT, 0, stream>>>(entries, bptr, ew_W1, ew_W2,
        x_, dinv, u_a, lin_W + 2*2*H*H, nullptr, gcn_b + 2*H, oW, nullptr, out);
}

// Round 11
// 579.157 us; speedup vs baseline: 1.7767x; 1.7754x over previous
//
#include <hip/hip_runtime.h>
#include <math.h>

#define N_NODES 100000
#define N_EDGES 3200000
#define H 10
#define S 12          // f32 node-table stride (48B)
#define SU 8          // packed-u stride in uints (32B)
#define IN_DIM 16
#define NBLK_SCAN 98  // ceil(100000/1024)
#define WPT 8         // lanes per node in gather passes

typedef int nint4 __attribute__((ext_vector_type(4)));

// ============ build phase: counting sort of edges by col (round-5, passing) ============

__global__ __launch_bounds__(256) void k_count(const int* __restrict__ ei,
                                               int* __restrict__ cnt)
{
    int e = blockIdx.x * 256 + threadIdx.x;
    if (e >= N_EDGES) return;
    atomicAdd(&cnt[ei[N_EDGES + e]], 1);
}

__global__ __launch_bounds__(1024) void k_scan1(const int* __restrict__ cnt,
    int* __restrict__ chunkscan, int* __restrict__ bsum)
{
    __shared__ int buf[2][1024];
    int tid = threadIdx.x;
    int gid = blockIdx.x * 1024 + tid;
    int v = (gid < N_NODES) ? cnt[gid] : 0;
    int cur = 0;
    buf[0][tid] = v;
    __syncthreads();
    int x = v;
    for (int off = 1; off < 1024; off <<= 1) {
        int t = (tid >= off) ? buf[cur][tid - off] : 0;
        x = buf[cur][tid] + t;
        buf[cur ^ 1][tid] = x;
        cur ^= 1;
        __syncthreads();
    }
    x = buf[cur][tid];
    if (gid < N_NODES) chunkscan[gid] = x - v;
    if (tid == 1023) bsum[blockIdx.x] = x;
}

__global__ __launch_bounds__(128) void k_scan2(int* __restrict__ bsum)
{
    __shared__ int buf[2][128];
    int tid = threadIdx.x;
    int v = (tid < NBLK_SCAN) ? bsum[tid] : 0;
    int cur = 0;
    buf[0][tid] = v;
    __syncthreads();
    int x = v;
    for (int off = 1; off < 128; off <<= 1) {
        int t = (tid >= off) ? buf[cur][tid - off] : 0;
        x = buf[cur][tid] + t;
        buf[cur ^ 1][tid] = x;
        cur ^= 1;
        __syncthreads();
    }
    x = buf[cur][tid];
    if (tid < NBLK_SCAN) bsum[tid] = x - v;
}

__global__ __launch_bounds__(256) void k_scan3(int* __restrict__ start,
    const int* __restrict__ bsum, int* __restrict__ ptr)
{
    int i = blockIdx.x * 256 + threadIdx.x;
    if (i >= N_NODES) return;
    int s = start[i] + bsum[i >> 10];
    start[i] = s;
    ptr[i] = s;
}

// ---- bf16 pack (round-to-nearest-even) / unpack ----
__device__ __forceinline__ unsigned pack2bf(float a, float b)
{
    unsigned ua = __float_as_uint(a), ub = __float_as_uint(b);
    unsigned ra = (ua + 0x7FFFu + ((ua >> 16) & 1u)) >> 16;
    unsigned rb = (ub + 0x7FFFu + ((ub >> 16) & 1u)) >> 16;
    return ra | (rb << 16);
}
__device__ __forceinline__ float bflo(unsigned v) { return __uint_as_float(v << 16); }
__device__ __forceinline__ float bfhi(unsigned v) { return __uint_as_float(v & 0xffff0000u); }

// entry = 16B: {bf16(a0,a1), bf16(a2,a3), row, 0}  (round-5, passing)
__global__ __launch_bounds__(256) void k_fill(const int* __restrict__ ei,
    const float* __restrict__ attr, int* __restrict__ ptr,
    nint4* __restrict__ entries)
{
    int e = blockIdx.x * 256 + threadIdx.x;
    if (e >= N_EDGES) return;
    int r = ei[e], c = ei[N_EDGES + e];
    float4 a = ((const float4*)attr)[e];
    int slot = atomicAdd(&ptr[c], 1);
    nint4 v;
    v.x = (int)pack2bf(a.x, a.y);
    v.y = (int)pack2bf(a.z, a.w);
    v.z = r;
    v.w = 0;
    __builtin_nontemporal_store(v, &entries[slot]);
}

// ============ shared helper: ew from packed attr ============
__device__ __forceinline__ void ew_from_packed(int px, int py,
    const float* sW1, const float* sW2, float ew[H])
{
    float ax = bflo((unsigned)px), ay = bfhi((unsigned)px);
    float az = bflo((unsigned)py), aw = bfhi((unsigned)py);
    float tt[H];
    #pragma unroll
    for (int j = 0; j < H; ++j)
        tt[j] = fmaxf(fmaf(ax, sW1[j], fmaf(ay, sW1[H+j],
                      fmaf(az, sW1[2*H+j], aw*sW1[3*H+j]))), 0.f);
    #pragma unroll
    for (int ch = 0; ch < H; ++ch) {
        float v = 0.f;
        #pragma unroll
        for (int j = 0; j < H; ++j) v = fmaf(tt[j], sW2[j*H + ch], v);
        ew[ch] = fmaxf(v, 0.f);
    }
}

// ============ deg pass (fused node init), WPT lanes/node ============
__global__ __launch_bounds__(256) void k_deg(const nint4* __restrict__ entries,
    const int* __restrict__ start, const int* __restrict__ cnt,
    const float* __restrict__ W1, const float* __restrict__ W2,
    const float* __restrict__ x, const float* __restrict__ iW,
    const float* __restrict__ ib, const float* __restrict__ gw0,
    float* __restrict__ x_, float* __restrict__ dinv, unsigned* __restrict__ u)
{
    __shared__ float sW1[4*H], sW2[H*H], siW[IN_DIM*H], sib[H], sgw[H];
    int tid = threadIdx.x;
    for (int k = tid; k < 4*H; k += 256) sW1[k] = W1[k];
    for (int k = tid; k < H*H; k += 256) sW2[k] = W2[k];
    for (int k = tid; k < IN_DIM*H; k += 256) siW[k] = iW[k];
    if (tid < H) sib[tid] = ib[tid];
    if (tid >= 32 && tid < 32+H) sgw[tid-32] = gw0[tid-32];
    __syncthreads();
    int node = blockIdx.x * (256 / WPT) + (tid >> 3);
    int r = tid & (WPT - 1);
    if (node >= N_NODES) return;
    int st = start[node], n = cnt[node];
    float s[H];
    #pragma unroll
    for (int ch = 0; ch < H; ++ch) s[ch] = 0.f;
    for (int e = st + r; e < st + n; e += WPT) {
        nint4 ent = entries[e];
        float ew[H];
        ew_from_packed(ent.x, ent.y, sW1, sW2, ew);
        #pragma unroll
        for (int ch = 0; ch < H; ++ch) s[ch] += ew[ch];
    }
    #pragma unroll
    for (int ch = 0; ch < H; ++ch) {
        s[ch] += __shfl_xor(s[ch], 1);
        s[ch] += __shfl_xor(s[ch], 2);
        s[ch] += __shfl_xor(s[ch], 4);
    }
    // fused node init (redundant across the 8 lanes)
    const float4* xv = (const float4*)(x + (size_t)node * IN_DIM);
    float xi[IN_DIM];
    float4 a0 = xv[0], a1 = xv[1], a2 = xv[2], a3 = xv[3];
    xi[0]=a0.x; xi[1]=a0.y; xi[2]=a0.z; xi[3]=a0.w;
    xi[4]=a1.x; xi[5]=a1.y; xi[6]=a1.z; xi[7]=a1.w;
    xi[8]=a2.x; xi[9]=a2.y; xi[10]=a2.z; xi[11]=a2.w;
    xi[12]=a3.x; xi[13]=a3.y; xi[14]=a3.z; xi[15]=a3.w;
    float xb[H], dv[H], uu[H];
    #pragma unroll
    for (int j = 0; j < H; ++j) {
        float a = sib[j];
        #pragma unroll
        for (int k = 0; k < IN_DIM; ++k) a = fmaf(xi[k], siW[k*H + j], a);
        xb[j] = a;
    }
    #pragma unroll
    for (int ch = 0; ch < H; ++ch) {
        float di = rsqrtf(1.0f + s[ch]);   // deg >= 1 (self loop)
        dv[ch] = di;
        uu[ch] = di * fmaxf(xb[ch], 0.f) * sgw[ch];
    }
    float* xd = x_   + (size_t)node * S;
    float* dd = dinv + (size_t)node * S;
    unsigned* ud = u + (size_t)node * SU;
    if (r == 0) {
        *(float4*)(xd+0) = make_float4(xb[0],xb[1],xb[2],xb[3]);
        *(float4*)(dd+0) = make_float4(dv[0],dv[1],dv[2],dv[3]);
        *(uint4*)(ud)    = make_uint4(pack2bf(uu[0],uu[1]), pack2bf(uu[2],uu[3]),
                                      pack2bf(uu[4],uu[5]), pack2bf(uu[6],uu[7]));
    } else if (r == 1) {
        *(float4*)(xd+4) = make_float4(xb[4],xb[5],xb[6],xb[7]);
        *(float4*)(dd+4) = make_float4(dv[4],dv[5],dv[6],dv[7]);
        ud[4] = pack2bf(uu[8], uu[9]);
    } else if (r == 2) {
        *(float4*)(xd+8) = make_float4(xb[8],xb[9],0.f,0.f);
        *(float4*)(dd+8) = make_float4(dv[8],dv[9],0.f,0.f);
    }
}

// ============ fused layer, WPT lanes/node, packed-u gather ============
template<int LAST>
__global__ __launch_bounds__(256) void k_layer(const nint4* __restrict__ entries,
    const int* __restrict__ start, const int* __restrict__ cnt,
    const float* __restrict__ W1, const float* __restrict__ W2,
    const float* __restrict__ x_, const float* __restrict__ dinv,
    const unsigned* __restrict__ uin,
    const float* __restrict__ lin, const float* __restrict__ gw_next,
    const float* __restrict__ gb, const float* __restrict__ oW,
    unsigned* __restrict__ uout, float* __restrict__ out)
{
    __shared__ float sW1[4*H], sW2[H*H], slin[2*H*H], sgw[H], sgb[H], soW[4*H];
    int tid = threadIdx.x;
    for (int k = tid; k < 4*H; k += 256) sW1[k] = W1[k];
    for (int k = tid; k < H*H; k += 256) sW2[k] = W2[k];
    for (int k = tid; k < 2*H*H; k += 256) slin[k] = lin[k];
    if (tid < H) sgb[tid] = gb[tid];
    if (LAST) { if (tid < 4*H) soW[tid] = oW[tid]; }
    else      { if (tid >= 64 && tid < 64+H) sgw[tid-64] = gw_next[tid-64]; }
    __syncthreads();
    int node = blockIdx.x * (256 / WPT) + (tid >> 3);
    int r = tid & (WPT - 1);
    if (node >= N_NODES) return;
    int st = start[node], n = cnt[node];
    float s[H];
    #pragma unroll
    for (int ch = 0; ch < H; ++ch) s[ch] = 0.f;
    for (int e = st + r; e < st + n; e += WPT) {
        nint4 ent = entries[e];
        float ew[H];
        ew_from_packed(ent.x, ent.y, sW1, sW2, ew);
        const unsigned* up = uin + (size_t)ent.z * SU;
        uint4 w = *(const uint4*)up;
        unsigned w2 = up[4];
        float ur[H];
        ur[0]=bflo(w.x); ur[1]=bfhi(w.x);
        ur[2]=bflo(w.y); ur[3]=bfhi(w.y);
        ur[4]=bflo(w.z); ur[5]=bfhi(w.z);
        ur[6]=bflo(w.w); ur[7]=bfhi(w.w);
        ur[8]=bflo(w2);  ur[9]=bfhi(w2);
        #pragma unroll
        for (int ch = 0; ch < H; ++ch) s[ch] = fmaf(ew[ch], ur[ch], s[ch]);
    }
    #pragma unroll
    for (int ch = 0; ch < H; ++ch) {
        s[ch] += __shfl_xor(s[ch], 1);
        s[ch] += __shfl_xor(s[ch], 2);
        s[ch] += __shfl_xor(s[ch], 4);
    }
    // epilogue (all lanes redundantly)
    const float* xi = x_   + (size_t)node * S;
    const float* di = dinv + (size_t)node * S;
    const unsigned* us = uin + (size_t)node * SU;
    uint4 wv = *(const uint4*)us;
    unsigned wv2 = us[4];
    float ui[H];
    ui[0]=bflo(wv.x); ui[1]=bfhi(wv.x);
    ui[2]=bflo(wv.y); ui[3]=bfhi(wv.y);
    ui[4]=bflo(wv.z); ui[5]=bfhi(wv.z);
    ui[6]=bflo(wv.w); ui[7]=bfhi(wv.w);
    ui[8]=bflo(wv2);  ui[9]=bfhi(wv2);
    float xv[H], agg[H];
    #pragma unroll
    for (int ch = 0; ch < H; ++ch) {
        xv[ch] = xi[ch];
        agg[ch] = di[ch] * (s[ch] + ui[ch]) + sgb[ch];  // self-loop folded in
    }
    float h[H];
    #pragma unroll
    for (int j = 0; j < H; ++j) {
        float a = xv[j];                                 // residual
        #pragma unroll
        for (int k = 0; k < H; ++k) a = fmaf(xv[k], slin[k*H + j], a);
        #pragma unroll
        for (int k = 0; k < H; ++k) a = fmaf(agg[k], slin[(H+k)*H + j], a);
        h[j] = a;
    }
    if (!LAST) {
        float un[H];
        #pragma unroll
        for (int ch = 0; ch < H; ++ch)
            un[ch] = di[ch] * fmaxf(h[ch], 0.f) * sgw[ch];
        unsigned* ud = uout + (size_t)node * SU;
        if (r == 0)
            *(uint4*)ud = make_uint4(pack2bf(un[0],un[1]), pack2bf(un[2],un[3]),
                                     pack2bf(un[4],un[5]), pack2bf(un[6],un[7]));
        else if (r == 1)
            ud[4] = pack2bf(un[8], un[9]);
    } else {
        float z0 = 0.f, z1 = 0.f;
        #pragma unroll
        for (int k = 0; k < H; ++k) { z0 = fmaf(xv[k], soW[2*k],   z0);
                                      z1 = fmaf(xv[k], soW[2*k+1], z1); }
        #pragma unroll
        for (int k = 0; k < H; ++k) { float hr = fmaxf(h[k], 0.f);
                                      z0 = fmaf(hr, soW[2*(H+k)],   z0);
                                      z1 = fmaf(hr, soW[2*(H+k)+1], z1); }
        if (r == 0) out[node] = 1.0f / (1.0f + expf(z0 - z1));
    }
}

extern "C" void kernel_launch(void* const* d_in, const int* in_sizes, int n_in,
                              void* d_out, int out_size, void* d_ws, size_t ws_size,
                              hipStream_t stream)
{
    const float* x     = (const float*)d_in[0];
    const int*   ei    = (const int*)  d_in[1];
    const float* attr  = (const float*)d_in[2];
    const float* ew_W1 = (const float*)d_in[3];
    const float* ew_W2 = (const float*)d_in[4];
    const float* iW    = (const float*)d_in[5];
    const float* ib    = (const float*)d_in[6];
    const float* gcn_w = (const float*)d_in[7];
    const float* gcn_b = (const float*)d_in[8];
    const float* lin_W = (const float*)d_in[9];
    const float* oW    = (const float*)d_in[10];
    float* out = (float*)d_out;
    char* ws = (char*)d_ws;

    size_t o = 0;
    nint4* entries = (nint4*)(ws + o); o += (size_t)N_EDGES * 16;          // 51.2 MB
    float* x_   = (float*)(ws + o); o += (size_t)N_NODES * S * 4;          // 4.8 MB
    float* dinv = (float*)(ws + o); o += (size_t)N_NODES * S * 4;          // 4.8 MB
    unsigned* u_a = (unsigned*)(ws + o); o += (size_t)N_NODES * SU * 4;    // 3.2 MB
    unsigned* u_b = (unsigned*)(ws + o); o += (size_t)N_NODES * SU * 4;    // 3.2 MB
    int* cnt    = (int*)(ws + o); o += (size_t)N_NODES * 4;
    int* start  = (int*)(ws + o); o += (size_t)N_NODES * 4;
    int* ptr    = (int*)(ws + o); o += (size_t)N_NODES * 4;
    int* bsum   = (int*)(ws + o); o += 512;

    dim3 blk(256);
    dim3 egrid((N_EDGES + 255) / 256);
    dim3 ngrid((N_NODES + 255) / 256);
    dim3 ggrid((N_NODES * WPT + 255) / 256);   // 3125 blocks, 32 nodes each

    (void)hipMemsetAsync(cnt, 0, (size_t)N_NODES * 4, stream);
    k_count<<<egrid, blk, 0, stream>>>(ei, cnt);
    k_scan1<<<NBLK_SCAN, 1024, 0, stream>>>(cnt, start, bsum);
    k_scan2<<<1, 128, 0, stream>>>(bsum);
    k_scan3<<<ngrid, blk, 0, stream>>>(start, bsum, ptr);
    k_fill <<<egrid, blk, 0, stream>>>(ei, attr, ptr, entries);
    k_deg  <<<ggrid, blk, 0, stream>>>(entries, start, cnt, ew_W1, ew_W2,
                                       x, iW, ib, gcn_w, x_, dinv, u_a);
    // layer 0: reads u_a, writes u_b
    k_layer<0><<<ggrid, blk, 0, stream>>>(entries, start, cnt, ew_W1, ew_W2,
        x_, dinv, u_a, lin_W + 0*2*H*H, gcn_w + 1*H, gcn_b + 0*H, oW, u_b, out);
    // layer 1: reads u_b, writes u_a
    k_layer<0><<<ggrid, blk, 0, stream>>>(entries, start, cnt, ew_W1, ew_W2,
        x_, dinv, u_b, lin_W + 1*2*H*H, gcn_w + 2*H, gcn_b + 1*H, oW, u_a, out);
    // layer 2: reads u_a, writes out
    k_layer<1><<<ggrid, blk, 0, stream>>>(entries, start, cnt, ew_W1, ew_W2,
        x_, dinv, u_a, lin_W + 2*2*H*H, nullptr, gcn_b + 2*H, oW, nullptr, out);
}

// Round 12
// 314.303 us; speedup vs baseline: 3.2739x; 1.8427x over previous
//
#include <hip/hip_runtime.h>
#include <math.h>

#define N_NODES 100000
#define N_EDGES 3200000
#define H 10
#define S 12          // f32 node-table stride (48B)
#define SU 8          // packed-u stride in uints (32B)
#define IN_DIM 16
#define WPT 8         // lanes per node in gather passes
#define NB 128        // nodes per bucket
#define NBKT 782      // ceil(N_NODES / NB)
#define BCAP 4608     // edge capacity per bucket (mean 4092, +8 sigma)
#define FTILE 8192    // edges per fill block (32 per thread @256)
#define NFB 391       // ceil(N_EDGES / FTILE)

typedef int nint4 __attribute__((ext_vector_type(4)));

// ============ bptr init ============
__global__ __launch_bounds__(256) void k_binit(int* __restrict__ bptr)
{
    int i = blockIdx.x * 256 + threadIdx.x;
    if (i < NBKT) bptr[i] = i * BCAP;
}

// ---- bf16 pack (round-to-nearest-even) / unpack ----
__device__ __forceinline__ unsigned pack2bf(float a, float b)
{
    unsigned ua = __float_as_uint(a), ub = __float_as_uint(b);
    unsigned ra = (ua + 0x7FFFu + ((ua >> 16) & 1u)) >> 16;
    unsigned rb = (ub + 0x7FFFu + ((ub >> 16) & 1u)) >> 16;
    return ra | (rb << 16);
}
__device__ __forceinline__ float bflo(unsigned v) { return __uint_as_float(v << 16); }
__device__ __forceinline__ float bfhi(unsigned v) { return __uint_as_float(v & 0xffff0000u); }

// ============ fill phase 1: tile-sorted scatter into bucket regions ============
// (round-6 passing structure) entry = 16B {bf16(a0,a1), bf16(a2,a3), row, col_local}
__global__ __launch_bounds__(256) void k_fill1(const int* __restrict__ ei,
    const float* __restrict__ attr, int* __restrict__ bptr,
    nint4* __restrict__ stage)
{
    __shared__ int lcnt[NBKT];
    __shared__ int lbase[NBKT];
    int tid = threadIdx.x;
    int base = blockIdx.x * FTILE;
    for (int k = tid; k < NBKT; k += 256) lcnt[k] = 0;
    __syncthreads();
    int c[32];
    #pragma unroll
    for (int k = 0; k < 32; ++k) {
        int e = base + k * 256 + tid;
        c[k] = (e < N_EDGES) ? ei[N_EDGES + e] : -1;
        if (c[k] >= 0) atomicAdd(&lcnt[c[k] >> 7], 1);
    }
    __syncthreads();
    for (int k = tid; k < NBKT; k += 256) {
        int n = lcnt[k];
        lbase[k] = n ? atomicAdd(&bptr[k], n) : 0;   // absolute stage index
        lcnt[k] = 0;
    }
    __syncthreads();
    #pragma unroll
    for (int k = 0; k < 32; ++k) {
        if (c[k] < 0) continue;
        int e = base + k * 256 + tid;
        int b = c[k] >> 7;
        int slot = atomicAdd(&lcnt[b], 1);
        int dest = lbase[b] + slot;
        if (dest < (b + 1) * BCAP) {                  // overflow guard (never fires)
            float4 a = ((const float4*)attr)[e];
            nint4 v;
            v.x = (int)pack2bf(a.x, a.y);
            v.y = (int)pack2bf(a.z, a.w);
            v.z = ei[e];
            v.w = c[k] & (NB - 1);
            stage[dest] = v;
        }
    }
}

// ============ fill phase 2: per-bucket exact-CSR reorder + emit start/cnt ============
__global__ __launch_bounds__(256) void k_fill2(const nint4* __restrict__ stage,
    const int* __restrict__ bptr, nint4* __restrict__ entries,
    int* __restrict__ start, int* __restrict__ cnt)
{
    __shared__ int hist[NB];
    __shared__ int buf[2][NB];
    __shared__ int cur[NB];
    int tid = threadIdx.x;
    int b = blockIdx.x;
    if (tid < NB) hist[tid] = 0;
    __syncthreads();
    int st = b * BCAP;
    int en = min(bptr[b], st + BCAP);
    for (int e = st + tid; e < en; e += 256) {
        nint4 ent = stage[e];
        atomicAdd(&hist[ent.w & (NB - 1)], 1);
    }
    __syncthreads();
    if (tid < NB) buf[0][tid] = hist[tid];
    __syncthreads();
    int cs = 0;
    for (int off = 1; off < NB; off <<= 1) {
        if (tid < NB) {
            int t = (tid >= off) ? buf[cs][tid - off] : 0;
            buf[cs ^ 1][tid] = buf[cs][tid] + t;
        }
        cs ^= 1;
        __syncthreads();
    }
    if (tid < NB) {
        int ex = buf[cs][tid] - hist[tid];            // exclusive prefix
        cur[tid] = ex;
        int node = b * NB + tid;
        if (node < N_NODES) {
            start[node] = st + ex;
            cnt[node]   = hist[tid];
        }
    }
    __syncthreads();
    for (int e = st + tid; e < en; e += 256) {
        nint4 ent = stage[e];
        int v = ent.w & (NB - 1);
        int slot = st + atomicAdd(&cur[v], 1);
        entries[slot] = ent;                          // confined to ~72KB window
    }
}

// ============ shared helper: ew from packed attr ============
__device__ __forceinline__ void ew_from_packed(int px, int py,
    const float* sW1, const float* sW2, float ew[H])
{
    float ax = bflo((unsigned)px), ay = bfhi((unsigned)px);
    float az = bflo((unsigned)py), aw = bfhi((unsigned)py);
    float tt[H];
    #pragma unroll
    for (int j = 0; j < H; ++j)
        tt[j] = fmaxf(fmaf(ax, sW1[j], fmaf(ay, sW1[H+j],
                      fmaf(az, sW1[2*H+j], aw*sW1[3*H+j]))), 0.f);
    #pragma unroll
    for (int ch = 0; ch < H; ++ch) {
        float v = 0.f;
        #pragma unroll
        for (int j = 0; j < H; ++j) v = fmaf(tt[j], sW2[j*H + ch], v);
        ew[ch] = fmaxf(v, 0.f);
    }
}

// ============ deg pass (fused node init), WPT lanes/node — round-11 passing ============
__global__ __launch_bounds__(256) void k_deg(const nint4* __restrict__ entries,
    const int* __restrict__ start, const int* __restrict__ cnt,
    const float* __restrict__ W1, const float* __restrict__ W2,
    const float* __restrict__ x, const float* __restrict__ iW,
    const float* __restrict__ ib, const float* __restrict__ gw0,
    float* __restrict__ x_, float* __restrict__ dinv, unsigned* __restrict__ u)
{
    __shared__ float sW1[4*H], sW2[H*H], siW[IN_DIM*H], sib[H], sgw[H];
    int tid = threadIdx.x;
    for (int k = tid; k < 4*H; k += 256) sW1[k] = W1[k];
    for (int k = tid; k < H*H; k += 256) sW2[k] = W2[k];
    for (int k = tid; k < IN_DIM*H; k += 256) siW[k] = iW[k];
    if (tid < H) sib[tid] = ib[tid];
    if (tid >= 32 && tid < 32+H) sgw[tid-32] = gw0[tid-32];
    __syncthreads();
    int node = blockIdx.x * (256 / WPT) + (tid >> 3);
    int r = tid & (WPT - 1);
    if (node >= N_NODES) return;
    int st = start[node], n = cnt[node];
    float s[H];
    #pragma unroll
    for (int ch = 0; ch < H; ++ch) s[ch] = 0.f;
    for (int e = st + r; e < st + n; e += WPT) {
        nint4 ent = entries[e];
        float ew[H];
        ew_from_packed(ent.x, ent.y, sW1, sW2, ew);
        #pragma unroll
        for (int ch = 0; ch < H; ++ch) s[ch] += ew[ch];
    }
    #pragma unroll
    for (int ch = 0; ch < H; ++ch) {
        s[ch] += __shfl_xor(s[ch], 1);
        s[ch] += __shfl_xor(s[ch], 2);
        s[ch] += __shfl_xor(s[ch], 4);
    }
    const float4* xv = (const float4*)(x + (size_t)node * IN_DIM);
    float xi[IN_DIM];
    float4 a0 = xv[0], a1 = xv[1], a2 = xv[2], a3 = xv[3];
    xi[0]=a0.x; xi[1]=a0.y; xi[2]=a0.z; xi[3]=a0.w;
    xi[4]=a1.x; xi[5]=a1.y; xi[6]=a1.z; xi[7]=a1.w;
    xi[8]=a2.x; xi[9]=a2.y; xi[10]=a2.z; xi[11]=a2.w;
    xi[12]=a3.x; xi[13]=a3.y; xi[14]=a3.z; xi[15]=a3.w;
    float xb[H], dv[H], uu[H];
    #pragma unroll
    for (int j = 0; j < H; ++j) {
        float a = sib[j];
        #pragma unroll
        for (int k = 0; k < IN_DIM; ++k) a = fmaf(xi[k], siW[k*H + j], a);
        xb[j] = a;
    }
    #pragma unroll
    for (int ch = 0; ch < H; ++ch) {
        float di = rsqrtf(1.0f + s[ch]);   // deg >= 1 (self loop)
        dv[ch] = di;
        uu[ch] = di * fmaxf(xb[ch], 0.f) * sgw[ch];
    }
    float* xd = x_   + (size_t)node * S;
    float* dd = dinv + (size_t)node * S;
    unsigned* ud = u + (size_t)node * SU;
    if (r == 0) {
        *(float4*)(xd+0) = make_float4(xb[0],xb[1],xb[2],xb[3]);
        *(float4*)(dd+0) = make_float4(dv[0],dv[1],dv[2],dv[3]);
        *(uint4*)(ud)    = make_uint4(pack2bf(uu[0],uu[1]), pack2bf(uu[2],uu[3]),
                                      pack2bf(uu[4],uu[5]), pack2bf(uu[6],uu[7]));
    } else if (r == 1) {
        *(float4*)(xd+4) = make_float4(xb[4],xb[5],xb[6],xb[7]);
        *(float4*)(dd+4) = make_float4(dv[4],dv[5],dv[6],dv[7]);
        ud[4] = pack2bf(uu[8], uu[9]);
    } else if (r == 2) {
        *(float4*)(xd+8) = make_float4(xb[8],xb[9],0.f,0.f);
        *(float4*)(dd+8) = make_float4(dv[8],dv[9],0.f,0.f);
    }
}

// ============ fused layer, WPT lanes/node, packed-u gather — round-11 passing ============
template<int LAST>
__global__ __launch_bounds__(256) void k_layer(const nint4* __restrict__ entries,
    const int* __restrict__ start, const int* __restrict__ cnt,
    const float* __restrict__ W1, const float* __restrict__ W2,
    const float* __restrict__ x_, const float* __restrict__ dinv,
    const unsigned* __restrict__ uin,
    const float* __restrict__ lin, const float* __restrict__ gw_next,
    const float* __restrict__ gb, const float* __restrict__ oW,
    unsigned* __restrict__ uout, float* __restrict__ out)
{
    __shared__ float sW1[4*H], sW2[H*H], slin[2*H*H], sgw[H], sgb[H], soW[4*H];
    int tid = threadIdx.x;
    for (int k = tid; k < 4*H; k += 256) sW1[k] = W1[k];
    for (int k = tid; k < H*H; k += 256) sW2[k] = W2[k];
    for (int k = tid; k < 2*H*H; k += 256) slin[k] = lin[k];
    if (tid < H) sgb[tid] = gb[tid];
    if (LAST) { if (tid < 4*H) soW[tid] = oW[tid]; }
    else      { if (tid >= 64 && tid < 64+H) sgw[tid-64] = gw_next[tid-64]; }
    __syncthreads();
    int node = blockIdx.x * (256 / WPT) + (tid >> 3);
    int r = tid & (WPT - 1);
    if (node >= N_NODES) return;
    int st = start[node], n = cnt[node];
    float s[H];
    #pragma unroll
    for (int ch = 0; ch < H; ++ch) s[ch] = 0.f;
    for (int e = st + r; e < st + n; e += WPT) {
        nint4 ent = entries[e];
        float ew[H];
        ew_from_packed(ent.x, ent.y, sW1, sW2, ew);
        const unsigned* up = uin + (size_t)ent.z * SU;
        uint4 w = *(const uint4*)up;
        unsigned w2 = up[4];
        float ur[H];
        ur[0]=bflo(w.x); ur[1]=bfhi(w.x);
        ur[2]=bflo(w.y); ur[3]=bfhi(w.y);
        ur[4]=bflo(w.z); ur[5]=bfhi(w.z);
        ur[6]=bflo(w.w); ur[7]=bfhi(w.w);
        ur[8]=bflo(w2);  ur[9]=bfhi(w2);
        #pragma unroll
        for (int ch = 0; ch < H; ++ch) s[ch] = fmaf(ew[ch], ur[ch], s[ch]);
    }
    #pragma unroll
    for (int ch = 0; ch < H; ++ch) {
        s[ch] += __shfl_xor(s[ch], 1);
        s[ch] += __shfl_xor(s[ch], 2);
        s[ch] += __shfl_xor(s[ch], 4);
    }
    const float* xi = x_   + (size_t)node * S;
    const float* di = dinv + (size_t)node * S;
    const unsigned* us = uin + (size_t)node * SU;
    uint4 wv = *(const uint4*)us;
    unsigned wv2 = us[4];
    float ui[H];
    ui[0]=bflo(wv.x); ui[1]=bfhi(wv.x);
    ui[2]=bflo(wv.y); ui[3]=bfhi(wv.y);
    ui[4]=bflo(wv.z); ui[5]=bfhi(wv.z);
    ui[6]=bflo(wv.w); ui[7]=bfhi(wv.w);
    ui[8]=bflo(wv2);  ui[9]=bfhi(wv2);
    float xv[H], agg[H];
    #pragma unroll
    for (int ch = 0; ch < H; ++ch) {
        xv[ch] = xi[ch];
        agg[ch] = di[ch] * (s[ch] + ui[ch]) + sgb[ch];  // self-loop folded in
    }
    float h[H];
    #pragma unroll
    for (int j = 0; j < H; ++j) {
        float a = xv[j];                                 // residual
        #pragma unroll
        for (int k = 0; k < H; ++k) a = fmaf(xv[k], slin[k*H + j], a);
        #pragma unroll
        for (int k = 0; k < H; ++k) a = fmaf(agg[k], slin[(H+k)*H + j], a);
        h[j] = a;
    }
    if (!LAST) {
        float un[H];
        #pragma unroll
        for (int ch = 0; ch < H; ++ch)
            un[ch] = di[ch] * fmaxf(h[ch], 0.f) * sgw[ch];
        unsigned* ud = uout + (size_t)node * SU;
        if (r == 0)
            *(uint4*)ud = make_uint4(pack2bf(un[0],un[1]), pack2bf(un[2],un[3]),
                                     pack2bf(un[4],un[5]), pack2bf(un[6],un[7]));
        else if (r == 1)
            ud[4] = pack2bf(un[8], un[9]);
    } else {
        float z0 = 0.f, z1 = 0.f;
        #pragma unroll
        for (int k = 0; k < H; ++k) { z0 = fmaf(xv[k], soW[2*k],   z0);
                                      z1 = fmaf(xv[k], soW[2*k+1], z1); }
        #pragma unroll
        for (int k = 0; k < H; ++k) { float hr = fmaxf(h[k], 0.f);
                                      z0 = fmaf(hr, soW[2*(H+k)],   z0);
                                      z1 = fmaf(hr, soW[2*(H+k)+1], z1); }
        if (r == 0) out[node] = 1.0f / (1.0f + expf(z0 - z1));
    }
}

extern "C" void kernel_launch(void* const* d_in, const int* in_sizes, int n_in,
                              void* d_out, int out_size, void* d_ws, size_t ws_size,
                              hipStream_t stream)
{
    const float* x     = (const float*)d_in[0];
    const int*   ei    = (const int*)  d_in[1];
    const float* attr  = (const float*)d_in[2];
    const float* ew_W1 = (const float*)d_in[3];
    const float* ew_W2 = (const float*)d_in[4];
    const float* iW    = (const float*)d_in[5];
    const float* ib    = (const float*)d_in[6];
    const float* gcn_w = (const float*)d_in[7];
    const float* gcn_b = (const float*)d_in[8];
    const float* lin_W = (const float*)d_in[9];
    const float* oW    = (const float*)d_in[10];
    float* out = (float*)d_out;
    char* ws = (char*)d_ws;

    size_t o = 0;
    nint4* stage   = (nint4*)(ws + o); o += (size_t)NBKT * BCAP * 16;      // 57.7 MB
    nint4* entries = (nint4*)(ws + o); o += (size_t)NBKT * BCAP * 16;      // 57.7 MB
    float* x_   = (float*)(ws + o); o += (size_t)N_NODES * S * 4;          // 4.8 MB
    float* dinv = (float*)(ws + o); o += (size_t)N_NODES * S * 4;          // 4.8 MB
    unsigned* u_a = (unsigned*)(ws + o); o += (size_t)N_NODES * SU * 4;    // 3.2 MB
    unsigned* u_b = (unsigned*)(ws + o); o += (size_t)N_NODES * SU * 4;    // 3.2 MB
    int* cnt    = (int*)(ws + o); o += (size_t)N_NODES * 4;
    int* start  = (int*)(ws + o); o += (size_t)N_NODES * 4;
    int* bptr   = (int*)(ws + o); o += (size_t)NBKT * 4;

    dim3 blk(256);
    dim3 ggrid((N_NODES * WPT + 255) / 256);   // 3125 blocks, 32 nodes each

    k_binit<<<(NBKT + 255) / 256, blk, 0, stream>>>(bptr);
    k_fill1<<<NFB, blk, 0, stream>>>(ei, attr, bptr, stage);
    k_fill2<<<NBKT, blk, 0, stream>>>(stage, bptr, entries, start, cnt);

    k_deg  <<<ggrid, blk, 0, stream>>>(entries, start, cnt, ew_W1, ew_W2,
                                       x, iW, ib, gcn_w, x_, dinv, u_a);
    // layer 0: reads u_a, writes u_b
    k_layer<0><<<ggrid, blk, 0, stream>>>(entries, start, cnt, ew_W1, ew_W2,
        x_, dinv, u_a, lin_W + 0*2*H*H, gcn_w + 1*H, gcn_b + 0*H, oW, u_b, out);
    // layer 1: reads u_b, writes u_a
    k_layer<0><<<ggrid, blk, 0, stream>>>(entries, start, cnt, ew_W1, ew_W2,
        x_, dinv, u_b, lin_W + 1*2*H*H, gcn_w + 2*H, gcn_b + 1*H, oW, u_a, out);
    // layer 2: reads u_a, writes out
    k_layer<1><<<ggrid, blk, 0, stream>>>(entries, start, cnt, ew_W1, ew_W2,
        x_, dinv, u_a, lin_W + 2*2*H*H, nullptr, gcn_b + 2*H, oW, nullptr, out);
}